// Round 1
// baseline (493.420 us; speedup 1.0000x reference)
//
#include <hip/hip_runtime.h>

#define POOL 7
#define NROIS 512
#define IMG_H 200
#define IMG_W 200
#define IMG_C 256

// One block = one (box n, output row py). 448 threads = 7 waves.
//   wave id (tid>>6)  -> px (0..6)        [wave-uniform scalar math]
//   lane   (tid&63)   -> 4 channels via float4 (16 B/lane coalesced)
__global__ __launch_bounds__(448) void roi_crop_resize_kernel(
    const float* __restrict__ img,
    const float* __restrict__ rois,
    float* __restrict__ out)
{
    const int blk = blockIdx.x;
    const int n  = blk / POOL;      // linear box index 0..4095
    const int py = blk - n * POOL;  // output row 0..6
    const int tid = threadIdx.x;
    const int px = tid >> 6;        // wave-uniform
    const int c4 = (tid & 63) << 2; // channel offset (float4)

    const float* box = rois + (size_t)n * 4;
    const float by1 = box[0];
    const float bx1 = box[1];
    const float by2 = box[2];
    const float bx2 = box[3];
    const int b = n / NROIS;        // batch index

    // Replicate reference arithmetic order exactly.
    const float ys = by1 * (float)(IMG_H - 1)
                   + (float)py * ((by2 - by1) * (float)(IMG_H - 1) / (float)(POOL - 1));
    const float xs = bx1 * (float)(IMG_W - 1)
                   + (float)px * ((bx2 - bx1) * (float)(IMG_W - 1) / (float)(POOL - 1));

    const bool valid = (ys >= 0.0f) && (ys <= (float)(IMG_H - 1))
                    && (xs >= 0.0f) && (xs <= (float)(IMG_W - 1));

    float4 r = make_float4(0.f, 0.f, 0.f, 0.f);

    if (valid) {  // wave-uniform branch: no divergence
        const float y0f = floorf(ys);
        const float x0f = floorf(xs);
        const float fy = ys - y0f;
        const float fx = xs - x0f;

        int y0 = (int)y0f; y0 = min(max(y0, 0), IMG_H - 1);
        const int y1i = min(y0 + 1, IMG_H - 1);
        int x0 = (int)x0f; x0 = min(max(x0, 0), IMG_W - 1);
        const int x1i = min(x0 + 1, IMG_W - 1);

        const size_t rowStride = (size_t)IMG_W * IMG_C;
        const size_t base = (size_t)b * IMG_H * rowStride + (size_t)c4;
        const float* p00 = img + base + (size_t)y0  * rowStride + (size_t)x0  * IMG_C;
        const float* p01 = img + base + (size_t)y0  * rowStride + (size_t)x1i * IMG_C;
        const float* p10 = img + base + (size_t)y1i * rowStride + (size_t)x0  * IMG_C;
        const float* p11 = img + base + (size_t)y1i * rowStride + (size_t)x1i * IMG_C;

        const float4 v00 = *(const float4*)p00;
        const float4 v01 = *(const float4*)p01;
        const float4 v10 = *(const float4*)p10;
        const float4 v11 = *(const float4*)p11;

        // top = v00 + (v01-v00)*fx ; bot = v10 + (v11-v10)*fx ; out = top + (bot-top)*fy
        float tx, bx;
        tx = v00.x + (v01.x - v00.x) * fx;  bx = v10.x + (v11.x - v10.x) * fx;
        r.x = tx + (bx - tx) * fy;
        tx = v00.y + (v01.y - v00.y) * fx;  bx = v10.y + (v11.y - v10.y) * fx;
        r.y = tx + (bx - tx) * fy;
        tx = v00.z + (v01.z - v00.z) * fx;  bx = v10.z + (v11.z - v10.z) * fx;
        r.z = tx + (bx - tx) * fy;
        tx = v00.w + (v01.w - v00.w) * fx;  bx = v10.w + (v11.w - v10.w) * fx;
        r.w = tx + (bx - tx) * fy;
    }

    // out[n][py][px][c4..c4+3]
    float* o = out + (((size_t)n * POOL + py) * POOL + px) * IMG_C + c4;
    *(float4*)o = r;
}

extern "C" void kernel_launch(void* const* d_in, const int* in_sizes, int n_in,
                              void* d_out, int out_size, void* d_ws, size_t ws_size,
                              hipStream_t stream) {
    const float* img  = (const float*)d_in[0];
    const float* rois = (const float*)d_in[1];
    float* out = (float*)d_out;

    const int nBoxes = in_sizes[1] / 4;   // 8 * 512 = 4096
    const int grid = nBoxes * POOL;       // 28672 blocks

    roi_crop_resize_kernel<<<grid, 448, 0, stream>>>(img, rois, out);
}

// Round 2
// 490.990 us; speedup vs baseline: 1.0049x; 1.0049x over previous
//
#include <hip/hip_runtime.h>

#define POOL 7
#define NROIS 512
#define IMG_H 200
#define IMG_W 200
#define IMG_C 256

// One block = one (box n, output row py). 448 threads = 7 waves.
//   wave id (tid>>6)  -> px (0..6)        [wave-uniform scalar math]
//   lane   (tid&63)   -> 4 channels via float4 (16 B/lane coalesced)
//
// Block swizzle: HW assigns blockIdx.x round-robin to XCDs (bid & 7).
// We remap so all 7 blocks of a box land on the SAME XCD (box n -> XCD n&7)
// while keeping boxes (and hence batches) time-coherent across the grid,
// so a box's corner-row reuse is served by its XCD-local 4 MiB L2.
__global__ __launch_bounds__(448) void roi_crop_resize_kernel(
    const float* __restrict__ img,
    const float* __restrict__ rois,
    float* __restrict__ out,
    int nBoxes, int doSwz)
{
    int n, py;
    if (doSwz) {
        const int xcd  = blockIdx.x & 7;
        const int slot = blockIdx.x >> 3;
        n  = (slot / POOL) * 8 + xcd;
        py = slot - (slot / POOL) * POOL;
    } else {
        n  = blockIdx.x / POOL;
        py = blockIdx.x - n * POOL;
    }

    const int tid = threadIdx.x;
    const int px = tid >> 6;        // wave-uniform
    const int c4 = (tid & 63) << 2; // channel offset (float4)

    const float4 box = *(const float4*)(rois + (size_t)n * 4);
    const float by1 = box.x;
    const float bx1 = box.y;
    const float by2 = box.z;
    const float bx2 = box.w;
    const int b = n / NROIS;        // batch index

    // Replicate reference arithmetic order exactly.
    const float ys = by1 * (float)(IMG_H - 1)
                   + (float)py * ((by2 - by1) * (float)(IMG_H - 1) / (float)(POOL - 1));
    const float xs = bx1 * (float)(IMG_W - 1)
                   + (float)px * ((bx2 - bx1) * (float)(IMG_W - 1) / (float)(POOL - 1));

    const bool valid = (ys >= 0.0f) && (ys <= (float)(IMG_H - 1))
                    && (xs >= 0.0f) && (xs <= (float)(IMG_W - 1));

    float4 r = make_float4(0.f, 0.f, 0.f, 0.f);

    if (valid) {  // wave-uniform branch: no divergence
        const float y0f = floorf(ys);
        const float x0f = floorf(xs);
        const float fy = ys - y0f;
        const float fx = xs - x0f;

        int y0 = (int)y0f; y0 = min(max(y0, 0), IMG_H - 1);
        const int y1i = min(y0 + 1, IMG_H - 1);
        int x0 = (int)x0f; x0 = min(max(x0, 0), IMG_W - 1);
        const int x1i = min(x0 + 1, IMG_W - 1);

        const size_t rowStride = (size_t)IMG_W * IMG_C;
        const size_t base = (size_t)b * IMG_H * rowStride + (size_t)c4;
        const float* p00 = img + base + (size_t)y0  * rowStride + (size_t)x0  * IMG_C;
        const float* p01 = img + base + (size_t)y0  * rowStride + (size_t)x1i * IMG_C;
        const float* p10 = img + base + (size_t)y1i * rowStride + (size_t)x0  * IMG_C;
        const float* p11 = img + base + (size_t)y1i * rowStride + (size_t)x1i * IMG_C;

        const float4 v00 = *(const float4*)p00;
        const float4 v01 = *(const float4*)p01;
        const float4 v10 = *(const float4*)p10;
        const float4 v11 = *(const float4*)p11;

        // top = v00 + (v01-v00)*fx ; bot = v10 + (v11-v10)*fx ; out = top + (bot-top)*fy
        float tx, bx;
        tx = v00.x + (v01.x - v00.x) * fx;  bx = v10.x + (v11.x - v10.x) * fx;
        r.x = tx + (bx - tx) * fy;
        tx = v00.y + (v01.y - v00.y) * fx;  bx = v10.y + (v11.y - v10.y) * fx;
        r.y = tx + (bx - tx) * fy;
        tx = v00.z + (v01.z - v00.z) * fx;  bx = v10.z + (v11.z - v10.z) * fx;
        r.z = tx + (bx - tx) * fy;
        tx = v00.w + (v01.w - v00.w) * fx;  bx = v10.w + (v11.w - v10.w) * fx;
        r.w = tx + (bx - tx) * fy;
    }

    // out[n][py][px][c4..c4+3] — write-once stream: bypass caches (keep L2/LLC for img)
    float* o = out + (((size_t)n * POOL + py) * POOL + px) * IMG_C + c4;
    __builtin_nontemporal_store(r.x, o + 0);
    __builtin_nontemporal_store(r.y, o + 1);
    __builtin_nontemporal_store(r.z, o + 2);
    __builtin_nontemporal_store(r.w, o + 3);
}

extern "C" void kernel_launch(void* const* d_in, const int* in_sizes, int n_in,
                              void* d_out, int out_size, void* d_ws, size_t ws_size,
                              hipStream_t stream) {
    const float* img  = (const float*)d_in[0];
    const float* rois = (const float*)d_in[1];
    float* out = (float*)d_out;

    const int nBoxes = in_sizes[1] / 4;   // 8 * 512 = 4096
    const int grid = nBoxes * POOL;       // 28672 blocks
    const int doSwz = (nBoxes % 8 == 0) ? 1 : 0;  // swizzle needs nBoxes % 8 == 0

    roi_crop_resize_kernel<<<grid, 448, 0, stream>>>(img, rois, out, nBoxes, doSwz);
}

// Round 3
// 487.559 us; speedup vs baseline: 1.0120x; 1.0070x over previous
//
#include <hip/hip_runtime.h>

#define POOL 7
#define NROIS 512
#define IMG_H 200
#define IMG_W 200
#define IMG_C 256
#define NBINS 128

// Kernel A: per-batch counting sort of boxes by y-center into perm[].
// One block per batch, NROIS threads (one per box). Order within a bin is
// nondeterministic (atomics) but the main kernel's output is order-invariant.
__global__ __launch_bounds__(NROIS) void sort_boxes_kernel(
    const float* __restrict__ rois, int* __restrict__ perm)
{
    __shared__ int hist[NBINS];
    __shared__ int offs[NBINS];
    const int b = blockIdx.x;
    const int t = threadIdx.x;
    if (t < NBINS) hist[t] = 0;
    __syncthreads();

    const int n = b * NROIS + t;
    const float y1 = rois[(size_t)n * 4 + 0];
    const float y2 = rois[(size_t)n * 4 + 2];
    const float yc = 0.5f * (y1 + y2);
    int bin = (int)(yc * (float)NBINS);
    bin = min(max(bin, 0), NBINS - 1);
    const int rank = atomicAdd(&hist[bin], 1);
    __syncthreads();

    if (t == 0) {
        int acc = 0;
        for (int i = 0; i < NBINS; ++i) { offs[i] = acc; acc += hist[i]; }
    }
    __syncthreads();

    perm[b * NROIS + offs[bin] + rank] = n;
}

// Kernel B: one block = one (sorted-slot s, output row py). 448 threads = 7 waves.
//   wave id (tid>>6)  -> px (0..6)        [wave-uniform scalar math]
//   lane   (tid&63)   -> 4 channels via float4 (16 B/lane coalesced)
// Blocks run in ~dispatch order, so sorted-by-y boxes give concurrent blocks a
// narrow y-band working set -> L2/LLC serve the ~2.5x corner re-reads.
__global__ __launch_bounds__(448) void roi_crop_resize_kernel(
    const float* __restrict__ img,
    const float* __restrict__ rois,
    const int* __restrict__ perm,
    float* __restrict__ out)
{
    const int blk = blockIdx.x;
    const int s  = blk / POOL;
    const int py = blk - s * POOL;
    const int n  = perm[s];          // sorted box index

    const int tid = threadIdx.x;
    const int px = tid >> 6;         // wave-uniform
    const int c4 = (tid & 63) << 2;  // channel offset (float4)

    const float4 box = *(const float4*)(rois + (size_t)n * 4);
    const float by1 = box.x;
    const float bx1 = box.y;
    const float by2 = box.z;
    const float bx2 = box.w;
    const int b = n / NROIS;         // batch index

    // Replicate reference arithmetic order exactly.
    const float ys = by1 * (float)(IMG_H - 1)
                   + (float)py * ((by2 - by1) * (float)(IMG_H - 1) / (float)(POOL - 1));
    const float xs = bx1 * (float)(IMG_W - 1)
                   + (float)px * ((bx2 - bx1) * (float)(IMG_W - 1) / (float)(POOL - 1));

    const bool valid = (ys >= 0.0f) && (ys <= (float)(IMG_H - 1))
                    && (xs >= 0.0f) && (xs <= (float)(IMG_W - 1));

    float4 r = make_float4(0.f, 0.f, 0.f, 0.f);

    if (valid) {  // wave-uniform branch: no divergence
        const float y0f = floorf(ys);
        const float x0f = floorf(xs);
        const float fy = ys - y0f;
        const float fx = xs - x0f;

        int y0 = (int)y0f; y0 = min(max(y0, 0), IMG_H - 1);
        const int y1i = min(y0 + 1, IMG_H - 1);
        int x0 = (int)x0f; x0 = min(max(x0, 0), IMG_W - 1);
        const int x1i = min(x0 + 1, IMG_W - 1);

        const size_t rowStride = (size_t)IMG_W * IMG_C;
        const size_t base = (size_t)b * IMG_H * rowStride + (size_t)c4;
        const float* p00 = img + base + (size_t)y0  * rowStride + (size_t)x0  * IMG_C;
        const float* p01 = img + base + (size_t)y0  * rowStride + (size_t)x1i * IMG_C;
        const float* p10 = img + base + (size_t)y1i * rowStride + (size_t)x0  * IMG_C;
        const float* p11 = img + base + (size_t)y1i * rowStride + (size_t)x1i * IMG_C;

        const float4 v00 = *(const float4*)p00;
        const float4 v01 = *(const float4*)p01;
        const float4 v10 = *(const float4*)p10;
        const float4 v11 = *(const float4*)p11;

        // top = v00 + (v01-v00)*fx ; bot = v10 + (v11-v10)*fx ; out = top + (bot-top)*fy
        float tx, bx;
        tx = v00.x + (v01.x - v00.x) * fx;  bx = v10.x + (v11.x - v10.x) * fx;
        r.x = tx + (bx - tx) * fy;
        tx = v00.y + (v01.y - v00.y) * fx;  bx = v10.y + (v11.y - v10.y) * fx;
        r.y = tx + (bx - tx) * fy;
        tx = v00.z + (v01.z - v00.z) * fx;  bx = v10.z + (v11.z - v10.z) * fx;
        r.z = tx + (bx - tx) * fy;
        tx = v00.w + (v01.w - v00.w) * fx;  bx = v10.w + (v11.w - v10.w) * fx;
        r.w = tx + (bx - tx) * fy;
    }

    // out[n][py][px][c4..c4+3] — write-once stream: nontemporal (keep caches for img)
    float* o = out + (((size_t)n * POOL + py) * POOL + px) * IMG_C + c4;
    __builtin_nontemporal_store(r.x, o + 0);
    __builtin_nontemporal_store(r.y, o + 1);
    __builtin_nontemporal_store(r.z, o + 2);
    __builtin_nontemporal_store(r.w, o + 3);
}

extern "C" void kernel_launch(void* const* d_in, const int* in_sizes, int n_in,
                              void* d_out, int out_size, void* d_ws, size_t ws_size,
                              hipStream_t stream) {
    const float* img  = (const float*)d_in[0];
    const float* rois = (const float*)d_in[1];
    float* out = (float*)d_out;
    int*   perm = (int*)d_ws;             // nBoxes ints of scratch

    const int nBoxes   = in_sizes[1] / 4; // 8 * 512 = 4096
    const int nBatches = nBoxes / NROIS;  // 8

    sort_boxes_kernel<<<nBatches, NROIS, 0, stream>>>(rois, perm);

    const int grid = nBoxes * POOL;       // 28672 blocks
    roi_crop_resize_kernel<<<grid, 448, 0, stream>>>(img, rois, perm, out);
}